// Round 1
// baseline (595.750 us; speedup 1.0000x reference)
//
#include <hip/hip_runtime.h>
#include <stdint.h>

#define VOCAB  50257
#define HIDDEN 2048
#define NTOK   (8 * 2048)   // BATCH * SEQ
#define TOPK   256

// One block (256 threads = 4 waves) per token row.
// Each thread holds 8 elements of the row in registers as 48-bit composite
// keys: (sortable_f32 << 16) | (~idx & 0xFFFF).  Keys are all distinct, and
// descending key order == (value desc, index asc) == jax.lax.top_k order.
// Radix-select (8-bit digits, MSB first, early exit) finds the exact 256th
// largest key; the >=threshold set (exactly 256 keys) is bitonic-sorted in
// LDS and unpacked to (value, index).
__global__ __launch_bounds__(256) void topk_kernel(
    const int* __restrict__ ids,
    const float* __restrict__ W,
    float* __restrict__ out)
{
    const int t   = threadIdx.x;
    const int row = blockIdx.x;

    __shared__ uint32_t hist[256];
    __shared__ uint32_t scan[256];
    __shared__ uint64_t sel[256];
    __shared__ uint32_t s_digit, s_rem, s_all, s_cnt;

    const int id = ids[row];
    const float4* src = reinterpret_cast<const float4*>(W + (size_t)id * HIDDEN);
    // coalesced: 2 x float4 per thread covers the 2048-float row
    float4 a = src[t];
    float4 b = src[t + 256];

    float vals[8] = {a.x, a.y, a.z, a.w, b.x, b.y, b.z, b.w};
    uint64_t key[8];
#pragma unroll
    for (int e = 0; e < 8; ++e) {
        uint32_t u = __float_as_uint(vals[e]);
        // order-preserving f32 -> u32 map
        u = (u & 0x80000000u) ? ~u : (u | 0x80000000u);
        int idx = (e < 4) ? (4 * t + e) : (1024 + 4 * t + (e - 4));
        key[e] = ((uint64_t)u << 16) | (uint32_t)((~idx) & 0xFFFF);
    }

    // ---- radix select: find threshold key T = 256th largest ----
    uint64_t prefix = 0;   // digits above current position, identical across threads
    uint32_t rem    = TOPK;
    uint64_t T      = 0;

    for (int bp = 40; bp >= 0; bp -= 8) {
        hist[t] = 0;
        __syncthreads();
#pragma unroll
        for (int e = 0; e < 8; ++e) {
            if ((key[e] >> (bp + 8)) == prefix)
                atomicAdd(&hist[(uint32_t)(key[e] >> bp) & 0xFFu], 1u);
        }
        __syncthreads();
        // inclusive suffix sum: scan[d] = count of matching keys with digit >= d
        scan[t] = hist[t];
        __syncthreads();
        for (int off = 1; off < 256; off <<= 1) {
            uint32_t add = (t + off < 256) ? scan[t + off] : 0u;
            __syncthreads();
            scan[t] += add;
            __syncthreads();
        }
        uint32_t ge = scan[t];
        uint32_t gt = (t == 255) ? 0u : scan[t + 1];
        if (ge >= rem && gt < rem) {       // exactly one thread: the threshold digit
            s_digit = (uint32_t)t;
            s_rem   = rem - gt;            // still needed within this digit's group
            s_all   = ((rem - gt) == hist[t]) ? 1u : 0u;  // whole group selected?
        }
        __syncthreads();
        prefix = (prefix << 8) | s_digit;
        rem    = s_rem;
        uint32_t all = s_all;
        __syncthreads();
        if (all || bp == 0) {              // threshold fully determined
            T = prefix << bp;
            break;
        }
    }

    // ---- collect the exactly-256 keys >= T ----
    if (t == 0) s_cnt = 0;
    __syncthreads();
#pragma unroll
    for (int e = 0; e < 8; ++e) {
        if (key[e] >= T) {
            uint32_t p = atomicAdd(&s_cnt, 1u);
            if (p < 256u) sel[p] = key[e];
        }
    }
    __syncthreads();

    // ---- bitonic sort 256 keys descending ----
    for (int k2 = 2; k2 <= 256; k2 <<= 1) {
        for (int j = k2 >> 1; j > 0; j >>= 1) {
            int ixj = t ^ j;
            if (ixj > t) {
                uint64_t x = sel[t], y = sel[ixj];
                bool desc = ((t & k2) == 0);
                bool sw = desc ? (x < y) : (x > y);
                if (sw) { sel[t] = y; sel[ixj] = x; }
            }
            __syncthreads();
        }
    }

    // ---- unpack & store ----
    uint64_t kk = sel[t];
    uint32_t s  = (uint32_t)(kk >> 16);
    uint32_t u  = (s & 0x80000000u) ? (s & 0x7FFFFFFFu) : ~s;
    int idx     = (int)((~(uint32_t)kk) & 0xFFFF);

    out[(size_t)row * TOPK + t] = __uint_as_float(u);
    out[(size_t)NTOK * TOPK + (size_t)row * TOPK + t] = (float)idx;
}

extern "C" void kernel_launch(void* const* d_in, const int* in_sizes, int n_in,
                              void* d_out, int out_size, void* d_ws, size_t ws_size,
                              hipStream_t stream) {
    const int*   ids = (const int*)d_in[0];
    const float* W   = (const float*)d_in[1];
    // d_in[2] is k == 256, fixed shape; hard-coded as TOPK.
    float* out = (float*)d_out;

    topk_kernel<<<NTOK, 256, 0, stream>>>(ids, W, out);
}

// Round 2
// 534.954 us; speedup vs baseline: 1.1136x; 1.1136x over previous
//
#include <hip/hip_runtime.h>
#include <stdint.h>

#define VOCAB  50257
#define HIDDEN 2048
#define NTOK   (8 * 2048)   // BATCH * SEQ
#define TOPK   256
#define WPB    4            // independent waves (rows) per block

// One WAVE per row, fully wave-synchronous: zero __syncthreads in the kernel.
// Each lane holds 32 row elements as order-preserving sortable u32 in regs.
// Composite 48-bit key (sv<<16)|(~idx) is reconstructed on demand (idx is a
// pure function of lane/element slot). Radix-select (8-bit digits, MSB-first,
// early exit) via per-wave LDS histogram + in-register shfl suffix-scan finds
// the exact 256th-largest key; the exactly-256 selected keys are bitonic-
// sorted with 4 keys/lane using shfl_xor exchanges (no LDS, no barriers).

__device__ __forceinline__ void cmpex(uint64_t& a, uint64_t& b, bool desc) {
    // a sits at the lower network position; desc => keep max at a
    bool gt = a > b;               // keys are distinct, no equal case
    uint64_t mx = gt ? a : b;
    uint64_t mn = gt ? b : a;
    a = desc ? mx : mn;
    b = desc ? mn : mx;
}

__device__ __forceinline__ void step_xor(uint64_t& v, int r, int lane, int lx, int k) {
    uint64_t p = __shfl_xor(v, lx, 64);
    int i = lane * 4 + r;
    bool desc = ((i & k) == 0);
    bool low  = ((lane & lx) == 0);
    bool keep_max = (desc == low);
    bool gt = v > p;
    v = (keep_max == gt) ? v : p;
}

__global__ __launch_bounds__(256) void topk_kernel(
    const int* __restrict__ ids,
    const float* __restrict__ W,
    float* __restrict__ out)
{
    const int lane = threadIdx.x & 63;
    const int w    = threadIdx.x >> 6;
    const int row  = blockIdx.x * WPB + w;

    __shared__ uint32_t hist[WPB][256];
    __shared__ __align__(16) uint64_t sel[WPB][256];
    __shared__ uint32_t cnt[WPB];

    const int id = ids[row];
    const float4* src = (const float4*)(W + (size_t)id * HIDDEN);

    // ---- load row, map to order-preserving sortable u32 ----
    // element e = c*4 + j lives at row index idx = c*256 + lane*4 + j
    uint32_t sv[32];
#pragma unroll
    for (int c = 0; c < 8; ++c) {
        float4 v = src[c * 64 + lane];
        uint32_t u[4] = {__float_as_uint(v.x), __float_as_uint(v.y),
                         __float_as_uint(v.z), __float_as_uint(v.w)};
#pragma unroll
        for (int j = 0; j < 4; ++j) {
            uint32_t m = (u[j] & 0x80000000u) ? 0xFFFFFFFFu : 0x80000000u;
            sv[c * 4 + j] = u[j] ^ m;
        }
    }

    // ---- radix select over 48-bit keys (sv<<16)|(0xFFFF^idx) ----
    uint32_t active = 0xFFFFFFFFu;   // per-lane bitmask over its 32 elements
    uint32_t rem    = TOPK;
    uint64_t prefix = 0;
    uint64_t Tkey   = 0;
    bool done = false;

#pragma unroll
    for (int bp = 40; bp >= 0; bp -= 8) {
        if (!done) {
            // zero my wave's histogram slice (4 bins/lane)
            *(uint4*)&hist[w][lane * 4] = make_uint4(0u, 0u, 0u, 0u);
            __threadfence_block();
#pragma unroll
            for (int e = 0; e < 32; ++e) {
                if (active & (1u << e)) {
                    uint32_t d;
                    if (bp >= 16) {
                        d = (sv[e] >> (bp - 16)) & 0xFFu;
                    } else {
                        uint32_t idx = (uint32_t)((e >> 2) * 256 + lane * 4 + (e & 3));
                        d = ((0xFFFFu ^ idx) >> bp) & 0xFFu;
                    }
                    atomicAdd(&hist[w][d], 1u);
                }
            }
            __threadfence_block();

            // in-register suffix scan: lane owns bins 4*lane .. 4*lane+3
            uint4 h = *(uint4*)&hist[w][lane * 4];
            uint32_t s3 = h.w;
            uint32_t s2 = h.z + s3;
            uint32_t s1 = h.y + s2;
            uint32_t s0 = h.x + s1;
            uint32_t suf = s0;
#pragma unroll
            for (int off = 1; off < 64; off <<= 1) {
                uint32_t t2 = __shfl_down(suf, off, 64);
                suf += (lane + off < 64) ? t2 : 0u;
            }
            uint32_t above = suf - s0;   // total in bins owned by lanes > me

            uint32_t dsel = 0, grp = 0, nrem = 0;
            bool found = false;
            uint32_t hm[4] = {h.x, h.y, h.z, h.w};
            uint32_t sm[4] = {s0, s1, s2, s3};
#pragma unroll
            for (int m = 0; m < 4; ++m) {
                uint32_t ge = above + sm[m];
                uint32_t gt = ge - hm[m];
                if (ge >= rem && gt < rem) {
                    found = true;
                    dsel = (uint32_t)(lane * 4 + m);
                    grp  = hm[m];
                    nrem = rem - gt;
                }
            }
            uint64_t ball = __ballot(found);
            int srcl = __builtin_ctzll(ball);
            uint64_t pack = ((uint64_t)dsel << 32) | ((uint64_t)grp << 16) | nrem;
            pack = __shfl(pack, srcl, 64);
            dsel = (uint32_t)(pack >> 32);
            grp  = (uint32_t)((pack >> 16) & 0xFFFFu);
            nrem = (uint32_t)(pack & 0xFFFFu);

            prefix = (prefix << 8) | dsel;
            rem = nrem;
            if (grp == nrem) {
                Tkey = prefix << bp;   // whole group selected: threshold known
                done = true;
            } else {
                // keep only elements whose digit matches
#pragma unroll
                for (int e = 0; e < 32; ++e) {
                    if (active & (1u << e)) {
                        uint32_t d;
                        if (bp >= 16) {
                            d = (sv[e] >> (bp - 16)) & 0xFFu;
                        } else {
                            uint32_t idx = (uint32_t)((e >> 2) * 256 + lane * 4 + (e & 3));
                            d = ((0xFFFFu ^ idx) >> bp) & 0xFFu;
                        }
                        if (d != dsel) active &= ~(1u << e);
                    }
                }
            }
        }
    }

    // ---- collect the exactly-256 keys >= Tkey ----
    if (lane == 0) cnt[w] = 0;
    __threadfence_block();
#pragma unroll
    for (int e = 0; e < 32; ++e) {
        uint32_t idx = (uint32_t)((e >> 2) * 256 + lane * 4 + (e & 3));
        uint64_t kk = ((uint64_t)sv[e] << 16) | (uint64_t)(0xFFFFu ^ idx);
        if (kk >= Tkey) {
            uint32_t p = atomicAdd(&cnt[w], 1u);
            if (p < 256u) sel[w][p] = kk;
        }
    }
    __threadfence_block();

    // ---- bitonic sort 256 keys descending, 4 keys/lane, position i=lane*4+r ----
    uint64_t v0 = sel[w][lane * 4 + 0];
    uint64_t v1 = sel[w][lane * 4 + 1];
    uint64_t v2 = sel[w][lane * 4 + 2];
    uint64_t v3 = sel[w][lane * 4 + 3];

#pragma unroll
    for (int k = 2; k <= 256; k <<= 1) {
#pragma unroll
        for (int j = 128; j >= 4; j >>= 1) {
            if (j <= (k >> 1)) {
                int lx = j >> 2;
                step_xor(v0, 0, lane, lx, k);
                step_xor(v1, 1, lane, lx, k);
                step_xor(v2, 2, lane, lx, k);
                step_xor(v3, 3, lane, lx, k);
            }
        }
        if (k >= 4) {
            bool d02 = (((lane * 4 + 0) & k) == 0);
            bool d13 = (((lane * 4 + 1) & k) == 0);
            cmpex(v0, v2, d02);
            cmpex(v1, v3, d13);
        }
        bool d01 = (((lane * 4 + 0) & k) == 0);
        bool d23 = (((lane * 4 + 2) & k) == 0);
        cmpex(v0, v1, d01);
        cmpex(v2, v3, d23);
    }

    // ---- unpack & store (rank = lane*4 + r), coalesced float4 ----
    uint64_t kk[4] = {v0, v1, v2, v3};
    float ov[4], oi[4];
#pragma unroll
    for (int r = 0; r < 4; ++r) {
        uint32_t s = (uint32_t)(kk[r] >> 16);
        ov[r] = __uint_as_float((s & 0x80000000u) ? (s & 0x7FFFFFFFu) : ~s);
        oi[r] = (float)(0xFFFFu ^ (uint32_t)(kk[r] & 0xFFFFu));
    }
    float4* out_v = (float4*)(out + (size_t)row * TOPK);
    float4* out_i = (float4*)(out + (size_t)NTOK * TOPK + (size_t)row * TOPK);
    out_v[lane] = make_float4(ov[0], ov[1], ov[2], ov[3]);
    out_i[lane] = make_float4(oi[0], oi[1], oi[2], oi[3]);
}

extern "C" void kernel_launch(void* const* d_in, const int* in_sizes, int n_in,
                              void* d_out, int out_size, void* d_ws, size_t ws_size,
                              hipStream_t stream) {
    const int*   ids = (const int*)d_in[0];
    const float* W   = (const float*)d_in[1];
    // d_in[2] is k == 256 (fixed), hard-coded as TOPK
    float* out = (float*)d_out;

    topk_kernel<<<NTOK / WPB, 256, 0, stream>>>(ids, W, out);
}

// Round 3
// 515.598 us; speedup vs baseline: 1.1555x; 1.0375x over previous
//
#include <hip/hip_runtime.h>
#include <stdint.h>

#define VOCAB  50257
#define HIDDEN 2048
#define NTOK   (8 * 2048)   // BATCH * SEQ
#define TOPK   256
#define WPB    4            // independent waves (rows) per block

// One WAVE per row, zero barriers, zero atomics, zero LDS histogram.
// Each lane holds 32 row elements as order-preserving sortable u32 in regs.
// Threshold = bisection on the u32 value with ballot/popcount counting
// (v_cmp + scalar bcnt co-issue; count lands wave-uniform in an SGPR).
// Exact value-tie fallback ranks equals in index order via ballot prefixes.
// Selected 256 keys (value<<16 | ~idx) are placed in LDS via ballot-prefix
// positions and bitonic-sorted with 4 keys/lane using shfl_xor exchanges.

__device__ __forceinline__ void cmpex(uint64_t& a, uint64_t& b, bool desc) {
    bool gt = a > b;               // keys are distinct, no equal case
    uint64_t mx = gt ? a : b;
    uint64_t mn = gt ? b : a;
    a = desc ? mx : mn;
    b = desc ? mn : mx;
}

__device__ __forceinline__ void step_xor(uint64_t& v, int r, int lane, int lx, int k) {
    uint64_t p = __shfl_xor(v, lx, 64);
    int i = lane * 4 + r;
    bool desc = ((i & k) == 0);
    bool low  = ((lane & lx) == 0);
    bool keep_max = (desc == low);
    bool gt = v > p;
    v = (keep_max == gt) ? v : p;
}

__global__ __launch_bounds__(256) void topk_kernel(
    const int* __restrict__ ids,
    const float* __restrict__ W,
    float* __restrict__ out)
{
    const int lane = threadIdx.x & 63;
    const int w    = threadIdx.x >> 6;
    const int row  = blockIdx.x * WPB + w;

    __shared__ __align__(16) uint64_t sel[WPB][256];

    const int id = ids[row];
    const float4* src = (const float4*)(W + (size_t)id * HIDDEN);

    // ---- load row, map to order-preserving sortable u32 ----
    // element e = c*4 + j lives at row index idx = c*256 + lane*4 + j
    uint32_t sv[32];
#pragma unroll
    for (int c = 0; c < 8; ++c) {
        float4 v = src[c * 64 + lane];
        uint32_t u[4] = {__float_as_uint(v.x), __float_as_uint(v.y),
                         __float_as_uint(v.z), __float_as_uint(v.w)};
#pragma unroll
        for (int j = 0; j < 4; ++j) {
            uint32_t m = (u[j] & 0x80000000u) ? 0xFFFFFFFFu : 0x80000000u;
            sv[c * 4 + j] = u[j] ^ m;
        }
    }

    // ---- count_ge(T): wave-wide count of sv >= T (scalar pipe does the sums) ----
    auto count_ge = [&](uint32_t T) -> uint32_t {
        uint32_t tot = 0;
#pragma unroll
        for (int e = 0; e < 32; ++e)
            tot += (uint32_t)__popcll(__ballot(sv[e] >= T));
        return tot;
    };

    // ---- bisection for the top-k value threshold ----
    // invariant: count_ge(lo) >= TOPK, count_ge(hi+1) < TOPK
    uint32_t lo = 0u, hi = 0xFFFFFFFFu;
    uint32_t Tsel = 0u;
    bool exact = false;
    while (lo < hi) {
        uint32_t mid = lo + ((hi - lo) >> 1) + 1u;
        uint32_t c = count_ge(mid);
        if (c == TOPK) { Tsel = mid; exact = true; break; }
        if (c > TOPK) lo = mid; else hi = mid - 1u;
    }

    // ---- build per-lane selection bitmask over the 32 elements ----
    uint32_t selmask = 0u;
    if (exact) {
#pragma unroll
        for (int e = 0; e < 32; ++e)
            if (sv[e] >= Tsel) selmask |= (1u << e);
    } else {
        // value ties at the boundary: take all > vstar, plus the lowest-index equals
        uint32_t vstar = lo;
        uint32_t m = (vstar == 0xFFFFFFFFu) ? 0u : count_ge(vstar + 1u);
        uint32_t r = TOPK - m;                 // equals still needed, by index order
        const uint64_t below = (1ull << lane) - 1ull;
        uint32_t base = 0u;                    // equals in chunks already processed
        for (int c = 0; c < 8; ++c) {
            uint64_t bj[4];
            uint32_t pre = 0u;
#pragma unroll
            for (int j = 0; j < 4; ++j) {
                bj[j] = __ballot(sv[c * 4 + j] == vstar);
                pre += (uint32_t)__popcll(bj[j] & below);
            }
            uint32_t ownpref = 0u;
#pragma unroll
            for (int j = 0; j < 4; ++j) {
                int e = c * 4 + j;
                bool eq = (sv[e] == vstar);
                uint32_t rank = base + pre + ownpref;   // idx order: lane-major, j-minor
                if (sv[e] > vstar || (eq && rank < r)) selmask |= (1u << e);
                ownpref += eq ? 1u : 0u;
            }
#pragma unroll
            for (int j = 0; j < 4; ++j)
                base += (uint32_t)__popcll(bj[j]);
        }
    }

    // ---- scatter the exactly-256 selected keys into LDS (ballot-prefix, no atomics) ----
    const uint64_t below = (1ull << lane) - 1ull;
    uint32_t pbase = 0u;
#pragma unroll
    for (int e = 0; e < 32; ++e) {
        bool s = (selmask >> e) & 1u;
        uint64_t mm = __ballot(s);
        if (s) {
            uint32_t idx = (uint32_t)((e >> 2) * 256 + lane * 4 + (e & 3));
            uint64_t kk = ((uint64_t)sv[e] << 16) | (uint64_t)(0xFFFFu ^ idx);
            uint32_t p = pbase + (uint32_t)__popcll(mm & below);
            sel[w][p] = kk;
        }
        pbase += (uint32_t)__popcll(mm);
    }
    __threadfence_block();

    // ---- bitonic sort 256 keys descending, 4 keys/lane, position i=lane*4+r ----
    uint64_t v0 = sel[w][lane * 4 + 0];
    uint64_t v1 = sel[w][lane * 4 + 1];
    uint64_t v2 = sel[w][lane * 4 + 2];
    uint64_t v3 = sel[w][lane * 4 + 3];

#pragma unroll
    for (int k = 2; k <= 256; k <<= 1) {
#pragma unroll
        for (int j = 128; j >= 4; j >>= 1) {
            if (j <= (k >> 1)) {
                int lx = j >> 2;
                step_xor(v0, 0, lane, lx, k);
                step_xor(v1, 1, lane, lx, k);
                step_xor(v2, 2, lane, lx, k);
                step_xor(v3, 3, lane, lx, k);
            }
        }
        if (k >= 4) {
            bool d02 = (((lane * 4 + 0) & k) == 0);
            bool d13 = (((lane * 4 + 1) & k) == 0);
            cmpex(v0, v2, d02);
            cmpex(v1, v3, d13);
        }
        bool d01 = (((lane * 4 + 0) & k) == 0);
        bool d23 = (((lane * 4 + 2) & k) == 0);
        cmpex(v0, v1, d01);
        cmpex(v2, v3, d23);
    }

    // ---- unpack & store (rank = lane*4 + r), coalesced float4 ----
    uint64_t kk[4] = {v0, v1, v2, v3};
    float ov[4], oi[4];
#pragma unroll
    for (int r = 0; r < 4; ++r) {
        uint32_t s = (uint32_t)(kk[r] >> 16);
        ov[r] = __uint_as_float((s & 0x80000000u) ? (s & 0x7FFFFFFFu) : ~s);
        oi[r] = (float)(0xFFFFu ^ (uint32_t)(kk[r] & 0xFFFFu));
    }
    float4* out_v = (float4*)(out + (size_t)row * TOPK);
    float4* out_i = (float4*)(out + (size_t)NTOK * TOPK + (size_t)row * TOPK);
    out_v[lane] = make_float4(ov[0], ov[1], ov[2], ov[3]);
    out_i[lane] = make_float4(oi[0], oi[1], oi[2], oi[3]);
}

extern "C" void kernel_launch(void* const* d_in, const int* in_sizes, int n_in,
                              void* d_out, int out_size, void* d_ws, size_t ws_size,
                              hipStream_t stream) {
    const int*   ids = (const int*)d_in[0];
    const float* W   = (const float*)d_in[1];
    // d_in[2] is k == 256 (fixed), hard-coded as TOPK
    float* out = (float*)d_out;

    topk_kernel<<<NTOK / WPB, 256, 0, stream>>>(ids, W, out);
}